// Round 15
// baseline (305.384 us; speedup 1.0000x reference)
//
#include <hip/hip_runtime.h>

typedef __attribute__((ext_vector_type(8))) short bh8;
typedef __attribute__((ext_vector_type(4))) float f4;

#define DEVI static __device__ __forceinline__

DEVI unsigned short f2b(float f) {
  union { float f; unsigned u; } v; v.f = f;
  unsigned r = v.u + 0x7fffu + ((v.u >> 16) & 1u);
  return (unsigned short)(r >> 16);
}
DEVI float b2f(unsigned short h) {
  union { unsigned u; float f; } v; v.u = ((unsigned)h) << 16;
  return v.f;
}
DEVI f4 mfma16(bh8 a, bh8 b, f4 c) {
  return __builtin_amdgcn_mfma_f32_16x16x32_bf16(a, b, c, 0, 0, 0);
}
DEVI void gload_lds16(const unsigned short* g, unsigned short* l) {
  __builtin_amdgcn_global_load_lds(
      (const __attribute__((address_space(1))) void*)(g),
      (__attribute__((address_space(3))) void*)(l), 16, 0, 0);
}

// ============================ merged prep ============================
__global__ __launch_bounds__(256) void prep_all_kern(
    const float* __restrict__ q, const float* __restrict__ k, const float* __restrict__ v,
    const float* __restrict__ wq, const float* __restrict__ wk, const float* __restrict__ wv,
    const float* __restrict__ g_in_w, const float* __restrict__ g_out_w,
    const float* __restrict__ wo, const float* __restrict__ rel_k,
    const float* __restrict__ bgo, const float* __restrict__ bo,
    unsigned short* __restrict__ xq, unsigned short* __restrict__ xk, unsigned short* __restrict__ xv,
    unsigned short* __restrict__ Wq, unsigned short* __restrict__ Wk, unsigned short* __restrict__ Wv,
    unsigned short* __restrict__ Wo_, unsigned short* __restrict__ WgoT,
    unsigned short* __restrict__ Bfin, unsigned short* __restrict__ Rk,
    float* __restrict__ bias2) {
  if (blockIdx.x < 8192) {
    long i = ((long)blockIdx.x * 256 + threadIdx.x) * 4;
    float4 a = *(const float4*)(q + i);
    float4 b = *(const float4*)(k + i);
    float4 c = *(const float4*)(v + i);
    union { unsigned short s[4]; uint2 u; } pa, pb, pc;
    pa.s[0] = f2b(a.x); pa.s[1] = f2b(a.y); pa.s[2] = f2b(a.z); pa.s[3] = f2b(a.w);
    pb.s[0] = f2b(b.x); pb.s[1] = f2b(b.y); pb.s[2] = f2b(b.z); pb.s[3] = f2b(b.w);
    pc.s[0] = f2b(c.x); pc.s[1] = f2b(c.y); pc.s[2] = f2b(c.z); pc.s[3] = f2b(c.w);
    *(uint2*)(xq + i) = pa.u;
    *(uint2*)(xk + i) = pb.u;
    *(uint2*)(xv + i) = pc.u;
    return;
  }
  int bw = blockIdx.x - 8192;
  if (bw >= 2337) {
    int o = (bw - 2337) * 256 + threadIdx.x;
    if (o < 512) {
      const float* r = wo + (long)o * 512;
      float s = 0.f;
#pragma unroll 4
      for (int m = 0; m < 512; m += 4) {
        float4 a = *(const float4*)(r + m);
        float4 b = *(const float4*)(bgo + m);
        s += a.x * b.x + a.y * b.y + a.z * b.z + a.w * b.w;
      }
      bias2[o] = bo[o] + 0.3f * s;
    }
    return;
  }
  long i = ((long)bw * 256 + threadIdx.x) * 4;
  if (i >= 2392128L) return;
  if (i >= 2097152L && i < 2359296L) {  // WgoT scatter
    long off = i - 2097152L;
    int ii = (int)(off >> 9), p = (int)(off & 511);
    union { unsigned short s[4]; uint2 u; } w;
#pragma unroll
    for (int tt = 0; tt < 4; tt++) w.s[tt] = f2b(g_out_w[(p + tt) * 512 + ii]);
    *(uint2*)(WgoT + off) = w.u;
    return;
  }
  const float* src; unsigned short* dst; long off; float sc = 1.0f;
  if (i < 524288L)        { dst = Wq;  off = i; src = (i < 262144L) ? wq + i : g_in_w + (i - 262144L); }
  else if (i < 1048576L)  { long j = i - 524288L;  dst = Wk;  off = j; src = (j < 262144L) ? wk + j : g_in_w + j; }
  else if (i < 1572864L)  { long j = i - 1048576L; dst = Wv;  off = j; src = (j < 262144L) ? wv + j : g_in_w + 262144L + j; }
  else if (i < 1835008L)  { long j = i - 1572864L; dst = Wo_; off = j; src = wo + j; }
  else if (i < 2097152L)  { long j = i - 1835008L; int col = (int)(j >> 9), kk = (int)(j & 511);
                            dst = Bfin; off = (long)col * 1024 + kk; src = wo + j; sc = 0.7f; }
  else                    { long j = i - 2359296L; dst = Rk;  off = j; src = rel_k + j; }
  float4 f = *(const float4*)src;
  union { unsigned short s[4]; uint2 u; } p;
  p.s[0] = f2b(f.x * sc); p.s[1] = f2b(f.y * sc); p.s[2] = f2b(f.z * sc); p.s[3] = f2b(f.w * sc);
  *(uint2*)(dst + off) = p.u;
}

// ============================ merged projection GEMM (BK=64, R14 proven) ============================
__global__ __launch_bounds__(256) void gemm3_kern(
    const unsigned short* __restrict__ Xq, const unsigned short* __restrict__ Xk,
    const unsigned short* __restrict__ Xv,
    const unsigned short* __restrict__ Wq, const unsigned short* __restrict__ Wk,
    const unsigned short* __restrict__ Wv,
    const float* __restrict__ bq, const float* __restrict__ bk, const float* __restrict__ bv,
    const float* __restrict__ g_in_b,
    unsigned short* __restrict__ Yq, unsigned short* __restrict__ Yk_,
    unsigned short* __restrict__ Yvt_l, unsigned short* __restrict__ Yvt_g,
    const unsigned short* __restrict__ Wo_, const unsigned short* __restrict__ WgoT,
    unsigned short* __restrict__ Bfin) {
  __shared__ unsigned short lsA[128 * 64];
  __shared__ unsigned short lsB[128 * 64];
  const int t = threadIdx.x;
  const int lane = t & 63, w = t >> 6;
  const int l15 = lane & 15, g = lane >> 4, g4 = g * 4;
  const int n = blockIdx.x;

  const unsigned short *Ap, *Bp;
  const float *b0 = nullptr, *b1 = nullptr;
  int seg, rb, cb;
  if (n < 3072) {
    seg = n >> 10;
    int m = n & 1023;
    int x = m >> 3, c = m & 7;
    rb = (c * 16 + (x & 15)) * 128;
    cb = (x >> 4) * 128;
    Ap = (seg == 0) ? Xq : (seg == 1) ? Xk : Xv;
    Bp = (seg == 0) ? Wq : (seg == 1) ? Wk : Wv;
    b0 = (seg == 0) ? bq : (seg == 1) ? bk : bv;
    b1 = g_in_b + seg * 512;
  } else {
    seg = 3;
    int m2 = n - 3072;
    rb = (m2 & 3) * 128; cb = (m2 >> 2) * 128;
    Ap = Wo_; Bp = WgoT;
  }

  const int wr = (w >> 1) * 64, wc = (w & 1) * 64;
  const int tr = t >> 3;
  const int kci = ((t & 7) ^ (tr & 7)) * 8;
  const unsigned short* pa = Ap + (long)(rb + tr) * 512 + kci;
  const unsigned short* pb = Bp + (long)(cb + tr) * 512 + kci;

  f4 acc[4][4] = {};
  for (int k0 = 0; k0 < 512; k0 += 64) {
    __syncthreads();
#pragma unroll
    for (int p = 0; p < 4; p++) {
      gload_lds16(pa + k0 + (long)p * 32 * 512, lsA + p * 2048 + w * 512);
      gload_lds16(pb + k0 + (long)p * 32 * 512, lsB + p * 2048 + w * 512);
    }
    __syncthreads();
    bh8 af[2][4], bf[2][4];
#pragma unroll
    for (int kh = 0; kh < 2; kh++) {
#pragma unroll
      for (int m = 0; m < 4; m++) {
        int rl = wr + m * 16 + l15;
        af[kh][m] = *(const bh8*)(lsA + rl * 64 + (((kh * 4 + g) ^ (rl & 7)) * 8));
      }
#pragma unroll
      for (int nn = 0; nn < 4; nn++) {
        int rl = wc + nn * 16 + l15;
        bf[kh][nn] = *(const bh8*)(lsB + rl * 64 + (((kh * 4 + g) ^ (rl & 7)) * 8));
      }
    }
    __builtin_amdgcn_s_setprio(1);
#pragma unroll
    for (int m = 0; m < 4; m++)
#pragma unroll
      for (int nn = 0; nn < 4; nn++) {
        acc[m][nn] = mfma16(af[0][m], bf[0][nn], acc[m][nn]);
        acc[m][nn] = mfma16(af[1][m], bf[1][nn], acc[m][nn]);
      }
    __builtin_amdgcn_s_setprio(0);
  }

  if (seg == 3) {
#pragma unroll
    for (int m = 0; m < 4; m++)
#pragma unroll
      for (int nn = 0; nn < 4; nn++)
#pragma unroll
        for (int j = 0; j < 4; j++) {
          int row = rb + wr + m * 16 + g4 + j;
          int col = cb + wc + nn * 16 + l15;
          Bfin[(long)row * 1024 + 512 + col] = f2b(0.3f * acc[m][nn][j]);
        }
    return;
  }
  if (seg == 2) {
#pragma unroll
    for (int m = 0; m < 4; m++)
#pragma unroll
      for (int nn = 0; nn < 4; nn++) {
        int col = cb + wc + nn * 16 + l15;
        float bsv = (col < 512) ? b0[col] : b1[col - 512];
        unsigned r[4];
#pragma unroll
        for (int j = 0; j < 4; j++) {
          union { float f; unsigned u; } v; v.f = acc[m][nn][j] + bsv;
          r[j] = v.u + 0x7fffu + ((v.u >> 16) & 1u);
        }
        unsigned lo = (r[0] >> 16) | (r[1] & 0xffff0000u);
        unsigned hi = (r[2] >> 16) | (r[3] & 0xffff0000u);
        int row0 = rb + wr + m * 16 + g4;
        int bb = row0 >> 9, s = row0 & 511;
        if (col < 512) {
          int hh = col >> 6, d = col & 63;
          *(uint2*)(Yvt_l + (((long)(bb * 8 + hh) * 64 + d) << 9) + s) = make_uint2(lo, hi);
        } else {
          int c2 = col - 512, hg = c2 >> 7, dg = c2 & 127;
          *(uint2*)(Yvt_g + (((long)(bb * 4 + hg) * 128 + dg) << 9) + s) = make_uint2(lo, hi);
        }
      }
    return;
  }
  unsigned short* Yo = (seg == 0) ? Yq : Yk_;
#pragma unroll
  for (int m = 0; m < 4; m++)
#pragma unroll
    for (int nn = 0; nn < 4; nn++)
#pragma unroll
      for (int j = 0; j < 4; j++) {
        int row = rb + wr + m * 16 + g4 + j;
        int col = cb + wc + nn * 16 + l15;
        float v = acc[m][nn][j] + ((col < 512) ? b0[col] : b1[col - 512]);
        Yo[(long)row * 1024 + col] = f2b(v);
      }
}

// ============================ final GEMM (BK=64, R14 proven) ============================
__global__ __launch_bounds__(256) void gemm_fin_kern(
    const unsigned short* __restrict__ A, const unsigned short* __restrict__ Bw,
    const float* __restrict__ bias0, float* __restrict__ outf) {
  __shared__ unsigned short lsA[128 * 64];
  __shared__ unsigned short lsB[128 * 64];
  const int t = threadIdx.x;
  const int lane = t & 63, w = t >> 6;
  const int l15 = lane & 15, g = lane >> 4, g4 = g * 4;
  int n = blockIdx.x;
  int x = n >> 3, c = n & 7;
  const int rb = (c * 16 + (x & 15)) * 128;
  const int cb = (x >> 4) * 128;
  const int wr = (w >> 1) * 64, wc = (w & 1) * 64;
  const int tr = t >> 3;
  const int kci = ((t & 7) ^ (tr & 7)) * 8;

  const unsigned short* pa = A + (long)(rb + tr) * 1024 + kci;
  const unsigned short* pb = Bw + (long)(cb + tr) * 1024 + kci;

  f4 acc[4][4] = {};
  for (int k0 = 0; k0 < 1024; k0 += 64) {
    __syncthreads();
#pragma unroll
    for (int p = 0; p < 4; p++) {
      gload_lds16(pa + k0 + (long)p * 32 * 1024, lsA + p * 2048 + w * 512);
      gload_lds16(pb + k0 + (long)p * 32 * 1024, lsB + p * 2048 + w * 512);
    }
    __syncthreads();
    bh8 af[2][4], bf[2][4];
#pragma unroll
    for (int kh = 0; kh < 2; kh++) {
#pragma unroll
      for (int m = 0; m < 4; m++) {
        int rl = wr + m * 16 + l15;
        af[kh][m] = *(const bh8*)(lsA + rl * 64 + (((kh * 4 + g) ^ (rl & 7)) * 8));
      }
#pragma unroll
      for (int nn = 0; nn < 4; nn++) {
        int rl = wc + nn * 16 + l15;
        bf[kh][nn] = *(const bh8*)(lsB + rl * 64 + (((kh * 4 + g) ^ (rl & 7)) * 8));
      }
    }
    __builtin_amdgcn_s_setprio(1);
#pragma unroll
    for (int m = 0; m < 4; m++)
#pragma unroll
      for (int nn = 0; nn < 4; nn++) {
        acc[m][nn] = mfma16(af[0][m], bf[0][nn], acc[m][nn]);
        acc[m][nn] = mfma16(af[1][m], bf[1][nn], acc[m][nn]);
      }
    __builtin_amdgcn_s_setprio(0);
  }
#pragma unroll
  for (int m = 0; m < 4; m++)
#pragma unroll
    for (int nn = 0; nn < 4; nn++)
#pragma unroll
      for (int j = 0; j < 4; j++) {
        int row = rb + wr + m * 16 + g4 + j;
        int col = cb + wc + nn * 16 + l15;
        outf[(long)row * 512 + col] = acc[m][nn][j] + bias0[col];
      }
}

// ============================ local attention v7 (3 blocks/CU) ============================
// 8KB chunks (K: 8x[64 rows][64 d]; V: 8x[64 d][64 k]), dbuf, stage-under-compute.
// Wave w: mm = w>>2, col-slice (w&3)*16+l15. LDS ~51KB -> 3 blocks/CU.
// k-accumulation order unchanged vs v6 -> bitwise-identical output.
__global__ __launch_bounds__(512, 6) void attn_local_kern(
    const unsigned short* __restrict__ Yq, const unsigned short* __restrict__ Yk,
    const unsigned short* __restrict__ Yvt, const unsigned short* __restrict__ relk,
    unsigned short* __restrict__ outC) {
  __shared__ unsigned short kv[2][4096];    // 2 x 8KB chunk
  __shared__ unsigned short buf[32 * 524];  // qrel then probs
  __shared__ float redbuf[8][32];

  const int t = threadIdx.x, lane = t & 63, w = t >> 6;
  const int l15 = lane & 15, g = lane >> 4, g8 = g * 8;
  int n = blockIdx.x;
  int bid = (n & 7) * 512 + (n >> 3);       // XCD swizzle
  const int qt = bid & 15;
  const int h = (bid >> 4) & 7;
  const int b = bid >> 7;
  const int qb = qt * 32;
  const long base = ((long)(b * 512)) * 1024 + h * 64;
  const long vbase = ((long)(b * 8 + h)) * 64 * 512;
  const int mmq = w >> 2, wq4 = w & 3;

  // K chunk [64 rows][64 d]: thread t -> row t>>3, slot chunk t&7 holds
  // global d-chunk (t&7)^(row&7). One gload/thread (512x16B = 8KB).
#define STAGE_K(ROFF, BUF) { \
    int rr = t >> 3, c_ = t & 7; \
    gload_lds16(Yk + base + (long)((ROFF) + rr) * 1024 + ((c_ ^ (rr & 7)) * 8), \
                kv[BUF] + w * 512); }
  // V chunk [64 d][64 k of chunk KC]: thread t -> d = t>>3, slot c_=t&7 holds
  // global k-chunk c_^(d&7).
#define STAGE_V(KC, BUF) { \
    int dd_ = t >> 3, c_ = t & 7; \
    gload_lds16(Yvt + vbase + (long)dd_ * 512 + (KC) * 64 + ((c_ ^ (dd_ & 7)) * 8), \
                kv[BUF] + w * 512); }
#define QK(CH) { \
    int rl = wq4 * 16 + l15; \
    const unsigned short* kb_ = kv[(CH) & 1]; \
    bh8 k0 = *(const bh8*)(kb_ + rl * 64 + ((g ^ (rl & 7)) * 8)); \
    bh8 k1 = *(const bh8*)(kb_ + rl * 64 + (((g + 4) ^ (rl & 7)) * 8)); \
    f4 a = {}; \
    a = mfma16(qfm[0], k0, a); \
    a = mfma16(qfm[1], k1, a); \
    sc8[CH] = a; }
#define GATHER(CH) { \
    _Pragma("unroll") \
    for (int j = 0; j < 4; j++) { \
      int lr = mmq * 16 + g * 4 + j; \
      int rowb = lr * 524; \
      int idx = rowb + 256 - (qb + lr) + (CH) * 64 + wq4 * 16 + l15; \
      idx = idx < rowb ? rowb : idx; \
      idx = idx > rowb + 512 ? rowb + 512 : idx; \
      float p = exp2f(fmaf(sc8[CH][j], 0.18033688011112042f, b2f(buf[idx]))); \
      sc8[CH][j] = p; \
      rs[j] += p; \
    } }

  STAGE_K(0, 0);

  // Q fragment: own mm only (rows qb + mmq*16 + l15)
  bh8 qfm[2];
  {
    const unsigned short* qp = Yq + base + (long)(qb + mmq * 16 + l15) * 1024 + g8;
    qfm[0] = *(const bh8*)(qp);
    qfm[1] = *(const bh8*)(qp + 32);
  }

  // qrel = (Q @ relk^T)*LOG2E -> buf rows of own mm (overlaps K0 flight)
  for (int tt = wq4; tt < 33; tt += 4) {
    int ri = tt * 16 + l15; if (ri > 512) ri = 512;
    const unsigned short* rp = relk + ri * 64 + g8;
    bh8 rf0 = *(const bh8*)(rp), rf1 = *(const bh8*)(rp + 32);
    f4 a = {};
    a = mfma16(qfm[0], rf0, a);
    a = mfma16(qfm[1], rf1, a);
    int col = tt * 16 + l15;
    if (col < 524) {
#pragma unroll
      for (int j = 0; j < 4; j++)
        buf[(mmq * 16 + g * 4 + j) * 524 + col] = f2b(a[j] * 1.4426950408889634f);
    }
  }
  __syncthreads();  // B0: K0 staged + qrel visible

  f4 sc8[8];
  float rs[4] = {};

  // K pipeline: 8 chunks, stage next under QK+GATHER of current
#pragma unroll
  for (int c = 0; c < 8; c++) {
    if (c < 7) { STAGE_K((c + 1) * 64, (c + 1) & 1); }
    else       { STAGE_V(0, 0); }
    __builtin_amdgcn_s_setprio(1);
    QK(c);
    __builtin_amdgcn_s_setprio(0);
    GATHER(c);
    __syncthreads();
  }

  // row sums -> redbuf; probs into buf (qrel dead)
#pragma unroll
  for (int j = 0; j < 4; j++) {
    int lr = mmq * 16 + g * 4 + j;
    float s = rs[j];
    for (int d = 1; d < 16; d <<= 1) s += __shfl_xor(s, d, 64);
    if (l15 == 0) redbuf[w][lr] = s;
  }
#pragma unroll
  for (int ch = 0; ch < 8; ch++) {
    int col = ch * 64 + wq4 * 16 + l15;
#pragma unroll
    for (int j = 0; j < 4; j++)
      buf[(mmq * 16 + g * 4 + j) * 524 + col] = f2b(sc8[ch][j]);
  }
  __syncthreads();  // B: probs + redbuf visible, V0 staged

  const int mmw = w >> 2, dt = w & 3;
  const int dd = dt * 16 + l15;
  float rinvj[4];
#pragma unroll
  for (int j = 0; j < 4; j++) {
    int lr = mmw * 16 + g * 4 + j;
    float s = redbuf[mmw * 4 + 0][lr] + redbuf[mmw * 4 + 1][lr] +
              redbuf[mmw * 4 + 2][lr] + redbuf[mmw * 4 + 3][lr];
    rinvj[j] = __builtin_amdgcn_rcpf(s);
  }

  // V pipeline: 8 chunks, PV on chunk kc while kc+1 in flight
  f4 accO = {};
#pragma unroll
  for (int kc = 0; kc < 8; kc++) {
    if (kc < 7) { STAGE_V(kc + 1, (kc + 1) & 1); }
    const unsigned short* vb_ = kv[kc & 1];
    __builtin_amdgcn_s_setprio(1);
#pragma unroll
    for (int ks2 = 0; ks2 < 2; ks2++) {
      union { uint2 u[2]; bh8 v; } pa;
      const unsigned short* pp = buf + (mmw * 16 + l15) * 524 + kc * 64 + ks2 * 32 + g8;
      pa.u[0] = *(const uint2*)(pp);
      pa.u[1] = *(const uint2*)(pp + 4);
      bh8 vv = *(const bh8*)(vb_ + dd * 64 + (((ks2 * 4 + g) ^ (dd & 7)) * 8));
      accO = mfma16(pa.v, vv, accO);
    }
    __builtin_amdgcn_s_setprio(0);
    if (kc < 7) __syncthreads();
  }
#pragma unroll
  for (int j = 0; j < 4; j++) {
    int row = qb + mmw * 16 + g * 4 + j;
    outC[((long)(b * 512 + row)) * 1024 + h * 64 + dt * 16 + l15] = f2b(accO[j] * rinvj[j]);
  }
#undef STAGE_K
#undef STAGE_V
#undef QK
#undef GATHER
}

// ============================ global attention v3 (R13 proven) ============================
__global__ __launch_bounds__(512, 4) void attn_glob_kern(
    const unsigned short* __restrict__ Yq, const unsigned short* __restrict__ Yk,
    const unsigned short* __restrict__ Yvt, unsigned short* __restrict__ outC) {
  __shared__ unsigned short kv[2][8192];
  __shared__ unsigned short buf[32 * 520];
  __shared__ float redbuf[8][32];

  const int t = threadIdx.x, lane = t & 63, w = t >> 6;
  const int l15 = lane & 15, g = lane >> 4, g8 = g * 8;
  int n = blockIdx.x;
  int bid = (n & 7) * 256 + (n >> 3);
  const int qt = bid & 15;
  const int hg = (bid >> 4) & 3;
  const int b = bid >> 6;
  const int qb = qt * 32;
  const long base = ((long)(b * 512)) * 1024 + 512 + hg * 128;
  const long vgbase = ((long)(b * 4 + hg)) * 128 * 512;

#define STAGE_GK(KC, BUF) { \
    const int c_ = t & 15; \
    _Pragma("unroll") \
    for (int it = 0; it < 2; it++) { \
      int rr = it * 32 + (t >> 4); \
      gload_lds16(Yk + base + (long)((KC) * 64 + rr) * 1024 + ((c_ ^ (rr & 15)) * 8), \
                  kv[BUF] + it * 4096 + w * 512); \
    } }
#define STAGE_GV(KC, BUF) { \
    const int c_ = t & 7; \
    _Pragma("unroll") \
    for (int it = 0; it < 2; it++) { \
      int dd_ = it * 64 + (t >> 3); \
      gload_lds16(Yvt + vgbase + (long)dd_ * 512 + (KC) * 64 + ((c_ ^ (dd_ & 7)) * 8), \
                  kv[BUF] + it * 4096 + w * 512); \
    } }

  const int mmq = w >> 2, wq4 = w & 3;

  STAGE_GK(0, 0);

  bh8 qf[4];
  {
    const unsigned short* qp = Yq + base + (long)(qb + mmq * 16 + l15) * 1024 + g8;
#pragma unroll
    for (int ks = 0; ks < 4; ks++) qf[ks] = *(const bh8*)(qp + ks * 32);
  }
  __syncthreads();  // K0 staged

  f4 sc8[8];
#pragma unroll
  for (int kc = 0; kc < 8; kc++) {
    if (kc < 7) { STAGE_GK(kc + 1, (kc + 1) & 1); }
    else        { STAGE_GV(0, 0); }
    const unsigned short* kb_ = kv[kc & 1];
    const int rl = wq4 * 16 + l15;
    __builtin_amdgcn_s_setprio(1);
    f4 a = {};
#pragma unroll
    for (int ks = 0; ks < 4; ks++) {
      bh8 kf = *(const bh8*)(kb_ + rl * 128 + (((ks * 4 + g) ^ (rl & 15)) * 8));
      a = mfma16(qf[ks], kf, a);
    }
    sc8[kc] = a;
    __builtin_amdgcn_s_setprio(0);
    __syncthreads();
  }

#pragma unroll
  for (int j = 0; j < 4; j++) {
    int lr = mmq * 16 + g * 4 + j;
    float s = 0.f;
#pragma unroll
    for (int kc = 0; kc < 8; kc++) {
      float p = exp2f(sc8[kc][j] * 0.12751745334f);  // 1/sqrt(128)*log2(e)
      sc8[kc][j] = p;
      s += p;
    }
    for (int d = 1; d < 16; d <<= 1) s += __shfl_xor(s, d, 64);
    if (l15 == 0) redbuf[w][lr] = s;
  }
  __syncthreads();

#pragma unroll
  for (int kc = 0; kc < 8; kc++) {
    int col = kc * 64 + wq4 * 16 + l15;
#pragma unroll
    for (int j = 0; j < 4; j++)
      buf[(mmq * 16 + g * 4 + j) * 520 + col] = f2b(sc8[kc][j]);
  }
  float rinv[2][4];
#pragma unroll
  for (int mm = 0; mm < 2; mm++)
#pragma unroll
    for (int j = 0; j < 4; j++) {
      int lr = mm * 16 + g * 4 + j;
      float s = redbuf[mm * 4 + 0][lr] + redbuf[mm * 4 + 1][lr] +
                redbuf[mm * 4 + 2][lr] + redbuf[mm * 4 + 3][lr];
      rinv[mm][j] = __builtin_amdgcn_rcpf(s);
    }
  __syncthreads();

  const int dd = w * 16 + l15;
  f4 accO[2] = {};
#pragma unroll
  for (int kc = 0; kc < 8; kc++) {
    if (kc < 7) { STAGE_GV(kc + 1, (kc + 1) & 1); }
    const unsigned short* vb_ = kv[kc & 1];
    __builtin_amdgcn_s_setprio(1);
#pragma unroll
    for (int ks2 = 0; ks2 < 2; ks2++) {
      bh8 vv = *(const bh8*)(vb_ + dd * 64 + (((ks2 * 4 + g) ^ (dd & 7)) * 8));
#pragma unroll
      for (int mm = 0; mm < 2; mm++) {
        union { uint2 u[2]; bh8 v; } pa;
        const unsigned short* pp = buf + (mm * 16 + l15) * 520 + kc * 64 + ks2 * 32 + g8;
        pa.u[0] = *(const uint2*)(pp);
        pa.u[1] = *(const uint2*)(pp + 4);
        accO[mm] = mfma16(pa.v, vv, accO[mm]);
      }
    }
    __builtin_amdgcn_s_setprio(0);
    if (kc < 7) __syncthreads();
  }
#pragma unroll
  for (int mm = 0; mm < 2; mm++)
#pragma unroll
    for (int j = 0; j < 4; j++) {
      int row = qb + mm * 16 + g * 4 + j;
      outC[((long)(b * 512 + row)) * 1024 + 512 + hg * 128 + w * 16 + l15] = f2b(accO[mm][j] * rinv[mm][j]);
    }
#undef STAGE_GK
#undef STAGE_GV
}

// ============================ launch ============================
extern "C" void kernel_launch(void* const* d_in, const int* in_sizes, int n_in,
                              void* d_out, int out_size, void* d_ws, size_t ws_size,
                              hipStream_t stream) {
  const float* query = (const float*)d_in[0];
  const float* key   = (const float*)d_in[1];
  const float* value = (const float*)d_in[2];
  const float* wq = (const float*)d_in[3];   const float* bq = (const float*)d_in[4];
  const float* wk = (const float*)d_in[5];   const float* bk = (const float*)d_in[6];
  const float* wv = (const float*)d_in[7];   const float* bv = (const float*)d_in[8];
  const float* wo = (const float*)d_in[9];   const float* bo = (const float*)d_in[10];
  const float* rel_k = (const float*)d_in[11];
  const float* g_in_w = (const float*)d_in[12];  const float* g_in_b = (const float*)d_in[13];
  const float* g_out_w = (const float*)d_in[14]; const float* g_out_b = (const float*)d_in[15];

  unsigned short* p = (unsigned short*)d_ws;
  unsigned short* Xq = p;            p += 8388608;   // CAT spans Xq+Xk
  unsigned short* Xk = p;            p += 8388608;
  unsigned short* Xv = p;            p += 8388608;
  unsigned short* Yq = p;            p += 16777216;  // [16384][1024]
  unsigned short* Yk = p;            p += 16777216;
  unsigned short* Yvt_l = p;         p += 8388608;   // [b][h][64][512]
  unsigned short* Yvt_g = p;         p += 8388608;   // [b][hg][128][512]
  unsigned short* Wq = p;            p += 524288;
  unsigned short* Wk = p;            p += 524288;
  unsigned short* Wv = p;            p += 524288;
  unsigned short* Wo_ = p;           p += 262144;
  unsigned short* WgoT = p;          p += 262144;
  unsigned short* Bfin = p;          p += 524288;    // [512][1024]
  unsigned short* Rk = p;            p += 32832;
  float* bias2 = (float*)p;          p += 1024;
  unsigned short* CAT = Xq;                          // [16384][1024]

  prep_all_kern<<<10531, 256, 0, stream>>>(query, key, value,
                                           wq, wk, wv, g_in_w, g_out_w, wo, rel_k,
                                           g_out_b, bo,
                                           Xq, Xk, Xv, Wq, Wk, Wv, Wo_, WgoT, Bfin, Rk, bias2);

  gemm3_kern<<<3088, 256, 0, stream>>>(Xq, Xk, Xv, Wq, Wk, Wv, bq, bk, bv, g_in_b,
                                       Yq, Yk, Yvt_l, Yvt_g, Wo_, WgoT, Bfin);

  attn_local_kern<<<4096, 512, 0, stream>>>(Yq, Yk, Yvt_l, Rk, CAT);
  attn_glob_kern<<<2048, 512, 0, stream>>>(Yq, Yk, Yvt_g, CAT);

  gemm_fin_kern<<<512, 256, 0, stream>>>(CAT, Bfin, bias2, (float*)d_out);
}

// Round 16
// 288.807 us; speedup vs baseline: 1.0574x; 1.0574x over previous
//
#include <hip/hip_runtime.h>

typedef __attribute__((ext_vector_type(8))) short bh8;
typedef __attribute__((ext_vector_type(4))) float f4;

#define DEVI static __device__ __forceinline__

DEVI unsigned short f2b(float f) {
  union { float f; unsigned u; } v; v.f = f;
  unsigned r = v.u + 0x7fffu + ((v.u >> 16) & 1u);
  return (unsigned short)(r >> 16);
}
DEVI float b2f(unsigned short h) {
  union { unsigned u; float f; } v; v.u = ((unsigned)h) << 16;
  return v.f;
}
DEVI f4 mfma16(bh8 a, bh8 b, f4 c) {
  return __builtin_amdgcn_mfma_f32_16x16x32_bf16(a, b, c, 0, 0, 0);
}
DEVI void gload_lds16(const unsigned short* g, unsigned short* l) {
  __builtin_amdgcn_global_load_lds(
      (const __attribute__((address_space(1))) void*)(g),
      (__attribute__((address_space(3))) void*)(l), 16, 0, 0);
}

// ============================ merged prep ============================
__global__ __launch_bounds__(256) void prep_all_kern(
    const float* __restrict__ q, const float* __restrict__ k, const float* __restrict__ v,
    const float* __restrict__ wq, const float* __restrict__ wk, const float* __restrict__ wv,
    const float* __restrict__ g_in_w, const float* __restrict__ g_out_w,
    const float* __restrict__ wo, const float* __restrict__ rel_k,
    const float* __restrict__ bgo, const float* __restrict__ bo,
    unsigned short* __restrict__ xq, unsigned short* __restrict__ xk, unsigned short* __restrict__ xv,
    unsigned short* __restrict__ Wq, unsigned short* __restrict__ Wk, unsigned short* __restrict__ Wv,
    unsigned short* __restrict__ Wo_, unsigned short* __restrict__ WgoT,
    unsigned short* __restrict__ Bfin, unsigned short* __restrict__ Rk,
    float* __restrict__ bias2) {
  if (blockIdx.x < 8192) {
    long i = ((long)blockIdx.x * 256 + threadIdx.x) * 4;
    float4 a = *(const float4*)(q + i);
    float4 b = *(const float4*)(k + i);
    float4 c = *(const float4*)(v + i);
    union { unsigned short s[4]; uint2 u; } pa, pb, pc;
    pa.s[0] = f2b(a.x); pa.s[1] = f2b(a.y); pa.s[2] = f2b(a.z); pa.s[3] = f2b(a.w);
    pb.s[0] = f2b(b.x); pb.s[1] = f2b(b.y); pb.s[2] = f2b(b.z); pb.s[3] = f2b(b.w);
    pc.s[0] = f2b(c.x); pc.s[1] = f2b(c.y); pc.s[2] = f2b(c.z); pc.s[3] = f2b(c.w);
    *(uint2*)(xq + i) = pa.u;
    *(uint2*)(xk + i) = pb.u;
    *(uint2*)(xv + i) = pc.u;
    return;
  }
  int bw = blockIdx.x - 8192;
  if (bw >= 2337) {
    int o = (bw - 2337) * 256 + threadIdx.x;
    if (o < 512) {
      const float* r = wo + (long)o * 512;
      float s = 0.f;
#pragma unroll 4
      for (int m = 0; m < 512; m += 4) {
        float4 a = *(const float4*)(r + m);
        float4 b = *(const float4*)(bgo + m);
        s += a.x * b.x + a.y * b.y + a.z * b.z + a.w * b.w;
      }
      bias2[o] = bo[o] + 0.3f * s;
    }
    return;
  }
  long i = ((long)bw * 256 + threadIdx.x) * 4;
  if (i >= 2392128L) return;
  if (i >= 2097152L && i < 2359296L) {  // WgoT scatter
    long off = i - 2097152L;
    int ii = (int)(off >> 9), p = (int)(off & 511);
    union { unsigned short s[4]; uint2 u; } w;
#pragma unroll
    for (int tt = 0; tt < 4; tt++) w.s[tt] = f2b(g_out_w[(p + tt) * 512 + ii]);
    *(uint2*)(WgoT + off) = w.u;
    return;
  }
  const float* src; unsigned short* dst; long off; float sc = 1.0f;
  if (i < 524288L)        { dst = Wq;  off = i; src = (i < 262144L) ? wq + i : g_in_w + (i - 262144L); }
  else if (i < 1048576L)  { long j = i - 524288L;  dst = Wk;  off = j; src = (j < 262144L) ? wk + j : g_in_w + j; }
  else if (i < 1572864L)  { long j = i - 1048576L; dst = Wv;  off = j; src = (j < 262144L) ? wv + j : g_in_w + 262144L + j; }
  else if (i < 1835008L)  { long j = i - 1572864L; dst = Wo_; off = j; src = wo + j; }
  else if (i < 2097152L)  { long j = i - 1835008L; int col = (int)(j >> 9), kk = (int)(j & 511);
                            dst = Bfin; off = (long)col * 1024 + kk; src = wo + j; sc = 0.7f; }
  else                    { long j = i - 2359296L; dst = Rk;  off = j; src = rel_k + j; }
  float4 f = *(const float4*)src;
  union { unsigned short s[4]; uint2 u; } p;
  p.s[0] = f2b(f.x * sc); p.s[1] = f2b(f.y * sc); p.s[2] = f2b(f.z * sc); p.s[3] = f2b(f.w * sc);
  *(uint2*)(dst + off) = p.u;
}

// ============================ merged projection GEMM (BK=64, R14 proven) ============================
__global__ __launch_bounds__(256) void gemm3_kern(
    const unsigned short* __restrict__ Xq, const unsigned short* __restrict__ Xk,
    const unsigned short* __restrict__ Xv,
    const unsigned short* __restrict__ Wq, const unsigned short* __restrict__ Wk,
    const unsigned short* __restrict__ Wv,
    const float* __restrict__ bq, const float* __restrict__ bk, const float* __restrict__ bv,
    const float* __restrict__ g_in_b,
    unsigned short* __restrict__ Yq, unsigned short* __restrict__ Yk_,
    unsigned short* __restrict__ Yvt_l, unsigned short* __restrict__ Yvt_g,
    const unsigned short* __restrict__ Wo_, const unsigned short* __restrict__ WgoT,
    unsigned short* __restrict__ Bfin) {
  __shared__ unsigned short lsA[128 * 64];
  __shared__ unsigned short lsB[128 * 64];
  const int t = threadIdx.x;
  const int lane = t & 63, w = t >> 6;
  const int l15 = lane & 15, g = lane >> 4, g4 = g * 4;
  const int n = blockIdx.x;

  const unsigned short *Ap, *Bp;
  const float *b0 = nullptr, *b1 = nullptr;
  int seg, rb, cb;
  if (n < 3072) {
    seg = n >> 10;
    int m = n & 1023;
    int x = m >> 3, c = m & 7;
    rb = (c * 16 + (x & 15)) * 128;
    cb = (x >> 4) * 128;
    Ap = (seg == 0) ? Xq : (seg == 1) ? Xk : Xv;
    Bp = (seg == 0) ? Wq : (seg == 1) ? Wk : Wv;
    b0 = (seg == 0) ? bq : (seg == 1) ? bk : bv;
    b1 = g_in_b + seg * 512;
  } else {
    seg = 3;
    int m2 = n - 3072;
    rb = (m2 & 3) * 128; cb = (m2 >> 2) * 128;
    Ap = Wo_; Bp = WgoT;
  }

  const int wr = (w >> 1) * 64, wc = (w & 1) * 64;
  const int tr = t >> 3;
  const int kci = ((t & 7) ^ (tr & 7)) * 8;
  const unsigned short* pa = Ap + (long)(rb + tr) * 512 + kci;
  const unsigned short* pb = Bp + (long)(cb + tr) * 512 + kci;

  f4 acc[4][4] = {};
  for (int k0 = 0; k0 < 512; k0 += 64) {
    __syncthreads();
#pragma unroll
    for (int p = 0; p < 4; p++) {
      gload_lds16(pa + k0 + (long)p * 32 * 512, lsA + p * 2048 + w * 512);
      gload_lds16(pb + k0 + (long)p * 32 * 512, lsB + p * 2048 + w * 512);
    }
    __syncthreads();
    bh8 af[2][4], bf[2][4];
#pragma unroll
    for (int kh = 0; kh < 2; kh++) {
#pragma unroll
      for (int m = 0; m < 4; m++) {
        int rl = wr + m * 16 + l15;
        af[kh][m] = *(const bh8*)(lsA + rl * 64 + (((kh * 4 + g) ^ (rl & 7)) * 8));
      }
#pragma unroll
      for (int nn = 0; nn < 4; nn++) {
        int rl = wc + nn * 16 + l15;
        bf[kh][nn] = *(const bh8*)(lsB + rl * 64 + (((kh * 4 + g) ^ (rl & 7)) * 8));
      }
    }
    __builtin_amdgcn_s_setprio(1);
#pragma unroll
    for (int m = 0; m < 4; m++)
#pragma unroll
      for (int nn = 0; nn < 4; nn++) {
        acc[m][nn] = mfma16(af[0][m], bf[0][nn], acc[m][nn]);
        acc[m][nn] = mfma16(af[1][m], bf[1][nn], acc[m][nn]);
      }
    __builtin_amdgcn_s_setprio(0);
  }

  if (seg == 3) {
#pragma unroll
    for (int m = 0; m < 4; m++)
#pragma unroll
      for (int nn = 0; nn < 4; nn++)
#pragma unroll
        for (int j = 0; j < 4; j++) {
          int row = rb + wr + m * 16 + g4 + j;
          int col = cb + wc + nn * 16 + l15;
          Bfin[(long)row * 1024 + 512 + col] = f2b(0.3f * acc[m][nn][j]);
        }
    return;
  }
  if (seg == 2) {
#pragma unroll
    for (int m = 0; m < 4; m++)
#pragma unroll
      for (int nn = 0; nn < 4; nn++) {
        int col = cb + wc + nn * 16 + l15;
        float bsv = (col < 512) ? b0[col] : b1[col - 512];
        unsigned r[4];
#pragma unroll
        for (int j = 0; j < 4; j++) {
          union { float f; unsigned u; } v; v.f = acc[m][nn][j] + bsv;
          r[j] = v.u + 0x7fffu + ((v.u >> 16) & 1u);
        }
        unsigned lo = (r[0] >> 16) | (r[1] & 0xffff0000u);
        unsigned hi = (r[2] >> 16) | (r[3] & 0xffff0000u);
        int row0 = rb + wr + m * 16 + g4;
        int bb = row0 >> 9, s = row0 & 511;
        if (col < 512) {
          int hh = col >> 6, d = col & 63;
          *(uint2*)(Yvt_l + (((long)(bb * 8 + hh) * 64 + d) << 9) + s) = make_uint2(lo, hi);
        } else {
          int c2 = col - 512, hg = c2 >> 7, dg = c2 & 127;
          *(uint2*)(Yvt_g + (((long)(bb * 4 + hg) * 128 + dg) << 9) + s) = make_uint2(lo, hi);
        }
      }
    return;
  }
  unsigned short* Yo = (seg == 0) ? Yq : Yk_;
#pragma unroll
  for (int m = 0; m < 4; m++)
#pragma unroll
    for (int nn = 0; nn < 4; nn++)
#pragma unroll
      for (int j = 0; j < 4; j++) {
        int row = rb + wr + m * 16 + g4 + j;
        int col = cb + wc + nn * 16 + l15;
        float v = acc[m][nn][j] + ((col < 512) ? b0[col] : b1[col - 512]);
        Yo[(long)row * 1024 + col] = f2b(v);
      }
}

// ============================ final GEMM (BK=64, R14 proven) ============================
__global__ __launch_bounds__(256) void gemm_fin_kern(
    const unsigned short* __restrict__ A, const unsigned short* __restrict__ Bw,
    const float* __restrict__ bias0, float* __restrict__ outf) {
  __shared__ unsigned short lsA[128 * 64];
  __shared__ unsigned short lsB[128 * 64];
  const int t = threadIdx.x;
  const int lane = t & 63, w = t >> 6;
  const int l15 = lane & 15, g = lane >> 4, g4 = g * 4;
  int n = blockIdx.x;
  int x = n >> 3, c = n & 7;
  const int rb = (c * 16 + (x & 15)) * 128;
  const int cb = (x >> 4) * 128;
  const int wr = (w >> 1) * 64, wc = (w & 1) * 64;
  const int tr = t >> 3;
  const int kci = ((t & 7) ^ (tr & 7)) * 8;

  const unsigned short* pa = A + (long)(rb + tr) * 1024 + kci;
  const unsigned short* pb = Bw + (long)(cb + tr) * 1024 + kci;

  f4 acc[4][4] = {};
  for (int k0 = 0; k0 < 1024; k0 += 64) {
    __syncthreads();
#pragma unroll
    for (int p = 0; p < 4; p++) {
      gload_lds16(pa + k0 + (long)p * 32 * 1024, lsA + p * 2048 + w * 512);
      gload_lds16(pb + k0 + (long)p * 32 * 1024, lsB + p * 2048 + w * 512);
    }
    __syncthreads();
    bh8 af[2][4], bf[2][4];
#pragma unroll
    for (int kh = 0; kh < 2; kh++) {
#pragma unroll
      for (int m = 0; m < 4; m++) {
        int rl = wr + m * 16 + l15;
        af[kh][m] = *(const bh8*)(lsA + rl * 64 + (((kh * 4 + g) ^ (rl & 7)) * 8));
      }
#pragma unroll
      for (int nn = 0; nn < 4; nn++) {
        int rl = wc + nn * 16 + l15;
        bf[kh][nn] = *(const bh8*)(lsB + rl * 64 + (((kh * 4 + g) ^ (rl & 7)) * 8));
      }
    }
    __builtin_amdgcn_s_setprio(1);
#pragma unroll
    for (int m = 0; m < 4; m++)
#pragma unroll
      for (int nn = 0; nn < 4; nn++) {
        acc[m][nn] = mfma16(af[0][m], bf[0][nn], acc[m][nn]);
        acc[m][nn] = mfma16(af[1][m], bf[1][nn], acc[m][nn]);
      }
    __builtin_amdgcn_s_setprio(0);
  }
#pragma unroll
  for (int m = 0; m < 4; m++)
#pragma unroll
    for (int nn = 0; nn < 4; nn++)
#pragma unroll
      for (int j = 0; j < 4; j++) {
        int row = rb + wr + m * 16 + g4 + j;
        int col = cb + wc + nn * 16 + l15;
        outf[(long)row * 512 + col] = acc[m][nn][j] + bias0[col];
      }
}

// ============================ merged attention (local v6 + glob v3) ============================
// 6144 blocks, 2:1 interleave: n%3<2 -> local id=grp*2+r3; n%3==2 -> glob id=grp.
// Both bodies bit-identical to R14's separate kernels (glob buf stride 520->524).
__global__ __launch_bounds__(512, 4) void attn_kern(
    const unsigned short* __restrict__ Yq, const unsigned short* __restrict__ Yk,
    const unsigned short* __restrict__ Yvt_l, const unsigned short* __restrict__ Yvt_g,
    const unsigned short* __restrict__ relk, unsigned short* __restrict__ outC) {
  __shared__ unsigned short kv[2][8192];
  __shared__ unsigned short buf[32 * 524];
  __shared__ float redbuf[8][32];

  const int t = threadIdx.x, lane = t & 63, w = t >> 6;
  const int l15 = lane & 15, g = lane >> 4, g8 = g * 8;
  const int n = blockIdx.x;
  const int grp = n / 3, r3 = n - grp * 3;

  if (r3 < 2) {
    // ==================== LOCAL (R14 v6) ====================
    int ln = grp * 2 + r3;
    int bid = (ln & 7) * 512 + (ln >> 3);
    const int qt = bid & 15;
    const int h = (bid >> 4) & 7;
    const int b = bid >> 7;
    const int qb = qt * 32;
    const long base = ((long)(b * 512)) * 1024 + h * 64;
    const long vbase = ((long)(b * 8 + h)) * 64 * 512;

#define STAGE_K(ROFF, BUF) { \
    const int c_ = t & 7; \
    _Pragma("unroll") \
    for (int it = 0; it < 2; it++) { \
      int rr = it * 64 + (t >> 3); \
      gload_lds16(Yk + base + (long)((ROFF) + rr) * 1024 + ((c_ ^ (rr & 7)) * 8), \
                  kv[BUF] + it * 4096 + w * 512); \
    } }
#define STAGE_V(COFF, BUF) { \
    const int c_ = t & 15; \
    _Pragma("unroll") \
    for (int it = 0; it < 2; it++) { \
      int dd_ = it * 32 + (t >> 4); \
      gload_lds16(Yvt_l + vbase + (long)dd_ * 512 + (COFF) + ((c_ ^ (dd_ & 15)) * 8), \
                  kv[BUF] + it * 4096 + w * 512); \
    } }
#define QK(CH) { \
    int rl = w * 16 + l15; \
    const unsigned short* kb_ = kv[(CH) & 1]; \
    bh8 k0 = *(const bh8*)(kb_ + rl * 64 + ((g ^ (rl & 7)) * 8)); \
    bh8 k1 = *(const bh8*)(kb_ + rl * 64 + (((g + 4) ^ (rl & 7)) * 8)); \
    _Pragma("unroll") \
    for (int mm = 0; mm < 2; mm++) { \
      f4 a = {}; \
      a = mfma16(qf[mm][0], k0, a); \
      a = mfma16(qf[mm][1], k1, a); \
      sc[mm][CH] = a; \
    } }
#define GATHER(CH) { \
    _Pragma("unroll") \
    for (int mm = 0; mm < 2; mm++) \
    _Pragma("unroll") \
    for (int j = 0; j < 4; j++) { \
      int lr = mm * 16 + g * 4 + j; \
      int rowb = lr * 524; \
      int idx = rowb + 256 - (qb + lr) + (CH) * 128 + w * 16 + l15; \
      idx = idx < rowb ? rowb : idx; \
      idx = idx > rowb + 512 ? rowb + 512 : idx; \
      float p = exp2f(fmaf(sc[mm][CH][j], 0.18033688011112042f, b2f(buf[idx]))); \
      sc[mm][CH][j] = p; \
      rs[mm][j] += p; \
    } }

    STAGE_K(0, 0);

    bh8 qf[2][2];
#pragma unroll
    for (int mm = 0; mm < 2; mm++) {
      const unsigned short* qp = Yq + base + (long)(qb + mm * 16 + l15) * 1024 + g8;
      qf[mm][0] = *(const bh8*)(qp);
      qf[mm][1] = *(const bh8*)(qp + 32);
    }

    for (int tt = w; tt < 33; tt += 8) {
      int ri = tt * 16 + l15; if (ri > 512) ri = 512;
      const unsigned short* rp = relk + ri * 64 + g8;
      bh8 rf0 = *(const bh8*)(rp), rf1 = *(const bh8*)(rp + 32);
      int col = tt * 16 + l15;
#pragma unroll
      for (int mm = 0; mm < 2; mm++) {
        f4 a = {};
        a = mfma16(qf[mm][0], rf0, a);
        a = mfma16(qf[mm][1], rf1, a);
        if (col < 524) {
#pragma unroll
          for (int j = 0; j < 4; j++)
            buf[(mm * 16 + g * 4 + j) * 524 + col] = f2b(a[j] * 1.4426950408889634f);
        }
      }
    }
    __syncthreads();

    f4 sc[2][4];
    float rs[2][4] = {};

#pragma unroll
    for (int c = 0; c < 4; c++) {
      if (c < 3) { STAGE_K((c + 1) * 128, (c + 1) & 1); }
      else       { STAGE_V(0, 0); }
      __builtin_amdgcn_s_setprio(1);
      QK(c);
      __builtin_amdgcn_s_setprio(0);
      GATHER(c);
      __syncthreads();
    }

#pragma unroll
    for (int mm = 0; mm < 2; mm++)
#pragma unroll
      for (int j = 0; j < 4; j++) {
        int lr = mm * 16 + g * 4 + j;
        float s = rs[mm][j];
        for (int d = 1; d < 16; d <<= 1) s += __shfl_xor(s, d, 64);
        if (l15 == 0) redbuf[w][lr] = s;
      }
#pragma unroll
    for (int mm = 0; mm < 2; mm++)
#pragma unroll
      for (int ch = 0; ch < 4; ch++) {
        int col = ch * 128 + w * 16 + l15;
#pragma unroll
        for (int j = 0; j < 4; j++)
          buf[(mm * 16 + g * 4 + j) * 524 + col] = f2b(sc[mm][ch][j]);
      }
    __syncthreads();

    const int mmw = w >> 2, dt = w & 3;
    const int dd = dt * 16 + l15;
    float rinvj[4];
#pragma unroll
    for (int j = 0; j < 4; j++) {
      int lr = mmw * 16 + g * 4 + j;
      float s = 0.f;
#pragma unroll
      for (int ww = 0; ww < 8; ww++) s += redbuf[ww][lr];
      rinvj[j] = __builtin_amdgcn_rcpf(s);
    }

    f4 accO = {};
#pragma unroll
    for (int d = 0; d < 4; d++) {
      if (d < 3) { STAGE_V((d + 1) * 128, (d + 1) & 1); }
      const unsigned short* vb_ = kv[d & 1];
      __builtin_amdgcn_s_setprio(1);
#pragma unroll
      for (int ks2 = 0; ks2 < 4; ks2++) {
        union { uint2 u[2]; bh8 v; } pa;
        const unsigned short* pp = buf + (mmw * 16 + l15) * 524 + (d * 4 + ks2) * 32 + g8;
        pa.u[0] = *(const uint2*)(pp);
        pa.u[1] = *(const uint2*)(pp + 4);
        bh8 vv = *(const bh8*)(vb_ + dd * 128 + (((ks2 * 4 + g) ^ (dd & 15)) * 8));
        accO = mfma16(pa.v, vv, accO);
      }
      __builtin_amdgcn_s_setprio(0);
      if (d < 3) __syncthreads();
    }
#pragma unroll
    for (int j = 0; j < 4; j++) {
      int row = qb + mmw * 16 + g * 4 + j;
      outC[((long)(b * 512 + row)) * 1024 + h * 64 + dt * 16 + l15] = f2b(accO[j] * rinvj[j]);
    }
#undef STAGE_K
#undef STAGE_V
#undef QK
#undef GATHER
  } else {
    // ==================== GLOBAL (R13/R14 v3; buf stride 524) ====================
    int gn = grp;
    int bid = (gn & 7) * 256 + (gn >> 3);
    const int qt = bid & 15;
    const int hg = (bid >> 4) & 3;
    const int b = bid >> 6;
    const int qb = qt * 32;
    const long base = ((long)(b * 512)) * 1024 + 512 + hg * 128;
    const long vgbase = ((long)(b * 4 + hg)) * 128 * 512;

#define STAGE_GK(KC, BUF) { \
    const int c_ = t & 15; \
    _Pragma("unroll") \
    for (int it = 0; it < 2; it++) { \
      int rr = it * 32 + (t >> 4); \
      gload_lds16(Yk + base + (long)((KC) * 64 + rr) * 1024 + ((c_ ^ (rr & 15)) * 8), \
                  kv[BUF] + it * 4096 + w * 512); \
    } }
#define STAGE_GV(KC, BUF) { \
    const int c_ = t & 7; \
    _Pragma("unroll") \
    for (int it = 0; it < 2; it++) { \
      int dd_ = it * 64 + (t >> 3); \
      gload_lds16(Yvt_g + vgbase + (long)dd_ * 512 + (KC) * 64 + ((c_ ^ (dd_ & 7)) * 8), \
                  kv[BUF] + it * 4096 + w * 512); \
    } }

    const int mmq = w >> 2, wq4 = w & 3;

    STAGE_GK(0, 0);

    bh8 qf[4];
    {
      const unsigned short* qp = Yq + base + (long)(qb + mmq * 16 + l15) * 1024 + g8;
#pragma unroll
      for (int ks = 0; ks < 4; ks++) qf[ks] = *(const bh8*)(qp + ks * 32);
    }
    __syncthreads();  // K0 staged

    f4 sc8[8];
#pragma unroll
    for (int kc = 0; kc < 8; kc++) {
      if (kc < 7) { STAGE_GK(kc + 1, (kc + 1) & 1); }
      else        { STAGE_GV(0, 0); }
      const unsigned short* kb_ = kv[kc & 1];
      const int rl = wq4 * 16 + l15;
      __builtin_amdgcn_s_setprio(1);
      f4 a = {};
#pragma unroll
      for (int ks = 0; ks < 4; ks++) {
        bh8 kf = *(const bh8*)(kb_ + rl * 128 + (((ks * 4 + g) ^ (rl & 15)) * 8));
        a = mfma16(qf[ks], kf, a);
      }
      sc8[kc] = a;
      __builtin_amdgcn_s_setprio(0);
      __syncthreads();
    }

#pragma unroll
    for (int j = 0; j < 4; j++) {
      int lr = mmq * 16 + g * 4 + j;
      float s = 0.f;
#pragma unroll
      for (int kc = 0; kc < 8; kc++) {
        float p = exp2f(sc8[kc][j] * 0.12751745334f);  // 1/sqrt(128)*log2(e)
        sc8[kc][j] = p;
        s += p;
      }
      for (int d = 1; d < 16; d <<= 1) s += __shfl_xor(s, d, 64);
      if (l15 == 0) redbuf[w][lr] = s;
    }
    __syncthreads();

#pragma unroll
    for (int kc = 0; kc < 8; kc++) {
      int col = kc * 64 + wq4 * 16 + l15;
#pragma unroll
      for (int j = 0; j < 4; j++)
        buf[(mmq * 16 + g * 4 + j) * 524 + col] = f2b(sc8[kc][j]);
    }
    float rinv[2][4];
#pragma unroll
    for (int mm = 0; mm < 2; mm++)
#pragma unroll
      for (int j = 0; j < 4; j++) {
        int lr = mm * 16 + g * 4 + j;
        float s = redbuf[mm * 4 + 0][lr] + redbuf[mm * 4 + 1][lr] +
                  redbuf[mm * 4 + 2][lr] + redbuf[mm * 4 + 3][lr];
        rinv[mm][j] = __builtin_amdgcn_rcpf(s);
      }
    __syncthreads();

    const int dd = w * 16 + l15;
    f4 accO[2] = {};
#pragma unroll
    for (int kc = 0; kc < 8; kc++) {
      if (kc < 7) { STAGE_GV(kc + 1, (kc + 1) & 1); }
      const unsigned short* vb_ = kv[kc & 1];
      __builtin_amdgcn_s_setprio(1);
#pragma unroll
      for (int ks2 = 0; ks2 < 2; ks2++) {
        bh8 vv = *(const bh8*)(vb_ + dd * 64 + (((ks2 * 4 + g) ^ (dd & 7)) * 8));
#pragma unroll
        for (int mm = 0; mm < 2; mm++) {
          union { uint2 u[2]; bh8 v; } pa;
          const unsigned short* pp = buf + (mm * 16 + l15) * 524 + kc * 64 + ks2 * 32 + g8;
          pa.u[0] = *(const uint2*)(pp);
          pa.u[1] = *(const uint2*)(pp + 4);
          accO[mm] = mfma16(pa.v, vv, accO[mm]);
        }
      }
      __builtin_amdgcn_s_setprio(0);
      if (kc < 7) __syncthreads();
    }
#pragma unroll
    for (int mm = 0; mm < 2; mm++)
#pragma unroll
      for (int j = 0; j < 4; j++) {
        int row = qb + mm * 16 + g * 4 + j;
        outC[((long)(b * 512 + row)) * 1024 + 512 + hg * 128 + w * 16 + l15] = f2b(accO[mm][j] * rinv[mm][j]);
      }
#undef STAGE_GK
#undef STAGE_GV
  }
}

// ============================ launch ============================
extern "C" void kernel_launch(void* const* d_in, const int* in_sizes, int n_in,
                              void* d_out, int out_size, void* d_ws, size_t ws_size,
                              hipStream_t stream) {
  const float* query = (const float*)d_in[0];
  const float* key   = (const float*)d_in[1];
  const float* value = (const float*)d_in[2];
  const float* wq = (const float*)d_in[3];   const float* bq = (const float*)d_in[4];
  const float* wk = (const float*)d_in[5];   const float* bk = (const float*)d_in[6];
  const float* wv = (const float*)d_in[7];   const float* bv = (const float*)d_in[8];
  const float* wo = (const float*)d_in[9];   const float* bo = (const float*)d_in[10];
  const float* rel_k = (const float*)d_in[11];
  const float* g_in_w = (const float*)d_in[12];  const float* g_in_b = (const float*)d_in[13];
  const float* g_out_w = (const float*)d_in[14]; const float* g_out_b = (const float*)d_in[15];

  unsigned short* p = (unsigned short*)d_ws;
  unsigned short* Xq = p;            p += 8388608;   // CAT spans Xq+Xk
  unsigned short* Xk = p;            p += 8388608;
  unsigned short* Xv = p;            p += 8388608;
  unsigned short* Yq = p;            p += 16777216;  // [16384][1024]
  unsigned short* Yk = p;            p += 16777216;
  unsigned short* Yvt_l = p;         p += 8388608;   // [b][h][64][512]
  unsigned short* Yvt_g = p;         p += 8388608;   // [b][hg][128][512]
  unsigned short* Wq = p;            p += 524288;
  unsigned short* Wk = p;            p += 524288;
  unsigned short* Wv = p;            p += 524288;
  unsigned short* Wo_ = p;           p += 262144;
  unsigned short* WgoT = p;          p += 262144;
  unsigned short* Bfin = p;          p += 524288;    // [512][1024]
  unsigned short* Rk = p;            p += 32832;
  float* bias2 = (float*)p;          p += 1024;
  unsigned short* CAT = Xq;                          // [16384][1024]

  prep_all_kern<<<10531, 256, 0, stream>>>(query, key, value,
                                           wq, wk, wv, g_in_w, g_out_w, wo, rel_k,
                                           g_out_b, bo,
                                           Xq, Xk, Xv, Wq, Wk, Wv, Wo_, WgoT, Bfin, Rk, bias2);

  gemm3_kern<<<3088, 256, 0, stream>>>(Xq, Xk, Xv, Wq, Wk, Wv, bq, bk, bv, g_in_b,
                                       Yq, Yk, Yvt_l, Yvt_g, Wo_, WgoT, Bfin);

  attn_kern<<<6144, 512, 0, stream>>>(Yq, Yk, Yvt_l, Yvt_g, Rk, CAT);

  gemm_fin_kern<<<512, 256, 0, stream>>>(CAT, Bfin, bias2, (float*)d_out);
}